// Round 4
// baseline (180.893 us; speedup 1.0000x reference)
//
#include <hip/hip_runtime.h>
#include <hip/hip_fp16.h>

// UVRenderer round 4: pass-split + paired-texel fp16 texture.
//   K1 build_ftab : face_uv + vertex_uv -> ftab[F] (3 pre-flipped UVs, 32 B/face)
//   K2 pack_tex   : uvmap [B,3,1024,1024] f32 -> ptex[b][y][x] = texels (x,x+1)
//                   as 6x fp16 in 16 B (one dwordx4 per bilinear row)
//   K3 uv_pass    : pix_to_face + bary + ftab -> clamped texel coords float2
//                   (x=-1 marks background)
//   K4 render     : 1-level chain: uv load -> 2 texture gathers -> blend -> store
// Fixed dims: B=4, H=W=Ht=Wt=1024, F=40000.

#define BB   4
#define HWT  (1 << 20)
#define WMASK 1023

static __device__ __forceinline__ unsigned h2bits(__half2 h) {
    return *reinterpret_cast<const unsigned*>(&h);
}

__global__ __launch_bounds__(256) void build_ftab(
    const int* __restrict__ face_uv, const float* __restrict__ vertex_uv,
    float4* __restrict__ ftab, int F)
{
    const int f = blockIdx.x * blockDim.x + threadIdx.x;
    if (f >= F) return;
    const int i0 = face_uv[f * 3 + 0];
    const int i1 = face_uv[f * 3 + 1];
    const int i2 = face_uv[f * 3 + 2];
    float4 a, b;
    a.x = vertex_uv[i0 * 2 + 0]; a.y = 1.0f - vertex_uv[i0 * 2 + 1];
    a.z = vertex_uv[i1 * 2 + 0]; a.w = 1.0f - vertex_uv[i1 * 2 + 1];
    b.x = vertex_uv[i2 * 2 + 0]; b.y = 1.0f - vertex_uv[i2 * 2 + 1];
    b.z = 0.0f; b.w = 0.0f;
    ftab[f * 2 + 0] = a;
    ftab[f * 2 + 1] = b;
}

__global__ __launch_bounds__(256) void pack_tex_pair(
    const float* __restrict__ uvmap, uint4* __restrict__ ptex)
{
    const int i = blockIdx.x * blockDim.x + threadIdx.x;  // 4M threads
    const int b  = i >> 20;
    const int hw = i & (HWT - 1);
    const int x  = hw & WMASK;
    const int hwr = (x < WMASK) ? hw + 1 : hw;
    const float* base = uvmap + ((size_t)b * 3 << 20);
    const float c0L = base[hw];
    const float c1L = base[HWT + hw];
    const float c2L = base[2 * HWT + hw];
    const float c0R = base[hwr];
    const float c1R = base[HWT + hwr];
    const float c2R = base[2 * HWT + hwr];
    uint4 q;
    q.x = h2bits(__floats2half2_rn(c0L, c1L));
    q.y = h2bits(__floats2half2_rn(c2L, c0R));
    q.z = h2bits(__floats2half2_rn(c1R, c2R));
    q.w = 0u;
    ptex[i] = q;
}

__global__ __launch_bounds__(256) void uv_pass(
    const float* __restrict__ bary, const float4* __restrict__ ftab,
    const int* __restrict__ pix_to_face, int F,
    float2* __restrict__ uvbuf)
{
    const int i = blockIdx.x * blockDim.x + threadIdx.x;  // 4M threads
    const int b = i >> 20;
    const int pf = pix_to_face[i];
    const bool valid = (pf != -1);
    const int local = valid ? pf - b * F : 0;   // face 0 for invalid (cached)
    const float4 A  = ftab[local * 2 + 0];
    const float4 Bv = ftab[local * 2 + 1];
    const float b0 = bary[(size_t)i * 3 + 0];
    const float b1 = bary[(size_t)i * 3 + 1];
    const float b2 = bary[(size_t)i * 3 + 2];
    const float u = b0 * A.x + b1 * A.z + b2 * Bv.x;
    const float v = b0 * A.y + b1 * A.w + b2 * Bv.y;
    float2 o;
    const float x = fminf(fmaxf(u * 1023.0f, 0.0f), 1023.0f);
    o.x = valid ? x : -1.0f;
    o.y = fminf(fmaxf(v * 1023.0f, 0.0f), 1023.0f);
    uvbuf[i] = o;
}

__global__ __launch_bounds__(256) void render_pass(
    const uint4* __restrict__ ptex, const float2* __restrict__ uvbuf,
    const float* __restrict__ bkg,
    float* __restrict__ render, float* __restrict__ is_valid)
{
    const int tid = blockIdx.x * blockDim.x + threadIdx.x;  // 1M threads, 4 px each
    const float bkg0 = bkg[0], bkg1 = bkg[1], bkg2 = bkg[2];

    // Phase 1: coalesced uv loads for all 4 batches.
    float2 uvp[4];
    #pragma unroll
    for (int j = 0; j < 4; ++j) uvp[j] = uvbuf[(j << 20) | tid];

    // Phase 2: issue all 8 texture gathers (invalid lanes read entry 0: L1 hit).
    uint4 q0[4], q1[4];
    float wx[4], wy[4];
    bool val[4];
    #pragma unroll
    for (int j = 0; j < 4; ++j) {
        float x = uvp[j].x, y = uvp[j].y;
        val[j] = (x >= 0.0f);
        x = val[j] ? x : 0.0f;
        const float xf = floorf(x), yf = floorf(y);
        const int x0 = (int)xf, y0 = (int)yf;
        const int y1 = min(y0 + 1, WMASK);
        wx[j] = x - xf; wy[j] = y - yf;
        const uint4* tb = ptex + (j << 20);
        q0[j] = tb[(y0 << 10) | x0];
        q1[j] = tb[(y1 << 10) | x0];
    }

    // Phase 3: unpack, blend, select, store.
    #pragma unroll
    for (int j = 0; j < 4; ++j) {
        const float2 t01 = __half22float2(*reinterpret_cast<const __half2*>(&q0[j].x));
        const float2 t2a = __half22float2(*reinterpret_cast<const __half2*>(&q0[j].y));
        const float2 t12 = __half22float2(*reinterpret_cast<const __half2*>(&q0[j].z));
        const float2 b01 = __half22float2(*reinterpret_cast<const __half2*>(&q1[j].x));
        const float2 b2a = __half22float2(*reinterpret_cast<const __half2*>(&q1[j].y));
        const float2 b12 = __half22float2(*reinterpret_cast<const __half2*>(&q1[j].z));
        const float iwx = 1.0f - wx[j], iwy = 1.0f - wy[j];
        // top row: L=(t01.x,t01.y,t2a.x)  R=(t2a.y,t12.x,t12.y)
        const float top0 = t01.x * iwx + t2a.y * wx[j];
        const float top1 = t01.y * iwx + t12.x * wx[j];
        const float top2 = t2a.x * iwx + t12.y * wx[j];
        const float bot0 = b01.x * iwx + b2a.y * wx[j];
        const float bot1 = b01.y * iwx + b12.x * wx[j];
        const float bot2 = b2a.x * iwx + b12.y * wx[j];
        float r0 = top0 * iwy + bot0 * wy[j];
        float r1 = top1 * iwy + bot1 * wy[j];
        float r2 = top2 * iwy + bot2 * wy[j];
        float vf = 1.0f;
        if (!val[j]) { r0 = bkg0; r1 = bkg1; r2 = bkg2; vf = 0.0f; }
        const int ob = (j * 3) << 20;
        __builtin_nontemporal_store(r0, &render[ob | tid]);
        __builtin_nontemporal_store(r1, &render[(ob + HWT) | tid]);
        __builtin_nontemporal_store(r2, &render[(ob + 2 * HWT) | tid]);
        __builtin_nontemporal_store(vf, &is_valid[(j << 20) | tid]);
    }
}

// ---------- fallback (ws too small): round-3 style single-texel path ----------
__global__ __launch_bounds__(256) void pack_tex_single(
    const float* __restrict__ uvmap, uint2* __restrict__ packed)
{
    const int total = BB * HWT;
    for (int i = blockIdx.x * blockDim.x + threadIdx.x; i < total;
         i += gridDim.x * blockDim.x) {
        const int b  = i >> 20;
        const int hw = i & (HWT - 1);
        const float* base = uvmap + (size_t)b * 3 * HWT + hw;
        uint2 t;
        t.x = h2bits(__floats2half2_rn(base[0], base[HWT]));
        t.y = h2bits(__floats2half2_rn(base[2 * (size_t)HWT], 0.0f));
        packed[i] = t;
    }
}

__global__ __launch_bounds__(256) void uvrender_fused(
    const float* __restrict__ bary, const uint2* __restrict__ ptex,
    const float* __restrict__ vertex_uv, const float* __restrict__ bkg,
    const int* __restrict__ pix_to_face, const int* __restrict__ face_uv,
    int F, float* __restrict__ render, float* __restrict__ is_valid)
{
    const int total = BB * HWT;
    const float bkg0 = bkg[0], bkg1 = bkg[1], bkg2 = bkg[2];
    for (int idx = blockIdx.x * blockDim.x + threadIdx.x; idx < total;
         idx += gridDim.x * blockDim.x) {
        const int b  = idx >> 20;
        const int hw = idx & (HWT - 1);
        const int pf = pix_to_face[idx];
        float r0 = bkg0, r1 = bkg1, r2 = bkg2, vflag = 0.0f;
        if (pf != -1) {
            vflag = 1.0f;
            const int local = pf - b * F;
            const int i0 = face_uv[local * 3 + 0];
            const int i1 = face_uv[local * 3 + 1];
            const int i2 = face_uv[local * 3 + 2];
            const float b0 = bary[(size_t)idx * 3 + 0];
            const float b1 = bary[(size_t)idx * 3 + 1];
            const float b2 = bary[(size_t)idx * 3 + 2];
            const float u = b0 * vertex_uv[i0 * 2] + b1 * vertex_uv[i1 * 2] +
                            b2 * vertex_uv[i2 * 2];
            const float v = b0 * (1.0f - vertex_uv[i0 * 2 + 1]) +
                            b1 * (1.0f - vertex_uv[i1 * 2 + 1]) +
                            b2 * (1.0f - vertex_uv[i2 * 2 + 1]);
            float x = fminf(fmaxf(u * 1023.0f, 0.0f), 1023.0f);
            float y = fminf(fmaxf(v * 1023.0f, 0.0f), 1023.0f);
            const float xf = floorf(x), yf = floorf(y);
            const int x0 = (int)xf, y0 = (int)yf;
            const int x1 = min(x0 + 1, WMASK), y1 = min(y0 + 1, WMASK);
            const float wx = x - xf, wy = y - yf;
            const float iwx = 1.0f - wx, iwy = 1.0f - wy;
            const uint2* tb = ptex + ((size_t)b << 20);
            const uint2 qa = tb[(y0 << 10) | x0];
            const uint2 qb = tb[(y0 << 10) | x1];
            const uint2 qc = tb[(y1 << 10) | x0];
            const uint2 qd = tb[(y1 << 10) | x1];
            #define U3(q, f0, f1, f2)                                            \
                { float2 _p = __half22float2(*reinterpret_cast<const __half2*>(&(q).x)); \
                  __half2 _h = *reinterpret_cast<const __half2*>(&(q).y);        \
                  f0 = _p.x; f1 = _p.y; f2 = __half2float(_h.x); }
            float a0,a1,a2, c0,c1,c2, d0,d1,d2, e0,e1,e2;
            U3(qa,a0,a1,a2); U3(qb,c0,c1,c2); U3(qc,d0,d1,d2); U3(qd,e0,e1,e2);
            #undef U3
            r0 = (a0*iwx + c0*wx)*iwy + (d0*iwx + e0*wx)*wy;
            r1 = (a1*iwx + c1*wx)*iwy + (d1*iwx + e1*wx)*wy;
            r2 = (a2*iwx + c2*wx)*iwy + (d2*iwx + e2*wx)*wy;
        }
        const size_t ob = (size_t)b * 3 * HWT + hw;
        __builtin_nontemporal_store(r0, &render[ob]);
        __builtin_nontemporal_store(r1, &render[ob + HWT]);
        __builtin_nontemporal_store(r2, &render[ob + 2 * (size_t)HWT]);
        __builtin_nontemporal_store(vflag, &is_valid[idx]);
    }
}

extern "C" void kernel_launch(void* const* d_in, const int* in_sizes, int n_in,
                              void* d_out, int out_size, void* d_ws, size_t ws_size,
                              hipStream_t stream) {
    const float* bary        = (const float*)d_in[0];
    const float* uvmap       = (const float*)d_in[1];
    const float* vertex_uv   = (const float*)d_in[2];
    const float* bkg         = (const float*)d_in[3];
    const int*   pix_to_face = (const int*)d_in[4];
    const int*   face_uv     = (const int*)d_in[5];
    const int F = in_sizes[5] / 3;   // == num_faces (40000)

    float* render   = (float*)d_out;
    float* is_valid = (float*)d_out + (size_t)BB * 3 * HWT;

    const size_t PTEX_B = (size_t)BB * HWT * sizeof(uint4);   // 64 MiB
    const size_t UV_B   = (size_t)BB * HWT * sizeof(float2);  // 32 MiB
    const size_t FTAB_B = (size_t)F * 2 * sizeof(float4);     // ~1.25 MiB

    if (ws_size >= PTEX_B + UV_B + FTAB_B) {
        uint4*  ptex  = (uint4*)d_ws;
        float2* uvbuf = (float2*)((char*)d_ws + PTEX_B);
        float4* ftab  = (float4*)((char*)d_ws + PTEX_B + UV_B);

        build_ftab<<<(F + 255) / 256, 256, 0, stream>>>(face_uv, vertex_uv, ftab, F);
        pack_tex_pair<<<(BB * HWT) / 256, 256, 0, stream>>>(uvmap, ptex);
        uv_pass<<<(BB * HWT) / 256, 256, 0, stream>>>(bary, ftab, pix_to_face, F, uvbuf);
        render_pass<<<HWT / 256, 256, 0, stream>>>(ptex, uvbuf, bkg, render, is_valid);
    } else {
        uint2* ptex = (uint2*)d_ws;  // 32 MiB
        pack_tex_single<<<2048, 256, 0, stream>>>(uvmap, ptex);
        uvrender_fused<<<2048, 256, 0, stream>>>(
            bary, ptex, vertex_uv, bkg, pix_to_face, face_uv, F, render, is_valid);
    }
}

// Round 5
// 137.654 us; speedup vs baseline: 1.3141x; 1.3141x over previous
//
#include <hip/hip_runtime.h>
#include <hip/hip_fp16.h>

// UVRenderer round 5: quad-texel texture (all 4 bilinear taps in one 32 B
// aligned record -> exactly one cache line per pixel gather), UV math fused
// back into the render pass (no uvbuf), ftab collapses face_uv+vertex_uv.
// Fixed dims: B=4, H=W=Ht=Wt=1024, F=40000.
//
// Record layout (per row, 12 B): w0=h2(c0_L,c1_L) w1=h2(c2_L,c0_R) w2=h2(c1_R,c2_R)
//   q32: 32 B entry = [row0 12B][pad 4][row1 12B][pad 4]   (two dwordx4)
//   q24: 24 B entry = [row0 12B][row1 12B]                 (six dwords)

#define BB   4
#define HWT  (1 << 20)
#define WMASK 1023

static __device__ __forceinline__ unsigned h2b(float a, float b) {
    __half2 h = __floats2half2_rn(a, b);
    return *reinterpret_cast<const unsigned*>(&h);
}
static __device__ __forceinline__ float2 h2f(unsigned u) {
    return __half22float2(*reinterpret_cast<const __half2*>(&u));
}

__global__ __launch_bounds__(256) void build_ftab(
    const int* __restrict__ face_uv, const float* __restrict__ vertex_uv,
    float4* __restrict__ ftab, int F)
{
    const int f = blockIdx.x * blockDim.x + threadIdx.x;
    if (f >= F) return;
    const int i0 = face_uv[f * 3 + 0];
    const int i1 = face_uv[f * 3 + 1];
    const int i2 = face_uv[f * 3 + 2];
    float4 a, b;
    a.x = vertex_uv[i0 * 2 + 0]; a.y = 1.0f - vertex_uv[i0 * 2 + 1];
    a.z = vertex_uv[i1 * 2 + 0]; a.w = 1.0f - vertex_uv[i1 * 2 + 1];
    b.x = vertex_uv[i2 * 2 + 0]; b.y = 1.0f - vertex_uv[i2 * 2 + 1];
    b.z = 0.0f; b.w = 0.0f;
    ftab[f * 2 + 0] = a;
    ftab[f * 2 + 1] = b;
}

template <bool PAD32>
__global__ __launch_bounds__(256) void pack_quad(
    const float* __restrict__ uvmap, unsigned* __restrict__ ptexu)
{
    const int i = blockIdx.x * blockDim.x + threadIdx.x;  // 4M
    const int b  = i >> 20;
    const int hw = i & (HWT - 1);
    const int x  = hw & WMASK;
    const int y  = hw >> 10;
    const int xr = min(x + 1, WMASK);
    const int yd = min(y + 1, WMASK);
    const float* base = uvmap + ((size_t)b * 3 << 20);
    const int iTL = (y  << 10) | x,  iTR = (y  << 10) | xr;
    const int iBL = (yd << 10) | x,  iBR = (yd << 10) | xr;
    const float c0TL = base[iTL],           c0TR = base[iTR];
    const float c1TL = base[HWT + iTL],     c1TR = base[HWT + iTR];
    const float c2TL = base[2 * HWT + iTL], c2TR = base[2 * HWT + iTR];
    const float c0BL = base[iBL],           c0BR = base[iBR];
    const float c1BL = base[HWT + iBL],     c1BR = base[HWT + iBR];
    const float c2BL = base[2 * HWT + iBL], c2BR = base[2 * HWT + iBR];

    const unsigned t0 = h2b(c0TL, c1TL), t1 = h2b(c2TL, c0TR), t2 = h2b(c1TR, c2TR);
    const unsigned u0 = h2b(c0BL, c1BL), u1 = h2b(c2BL, c0BR), u2 = h2b(c1BR, c2BR);

    if (PAD32) {
        uint4* p = reinterpret_cast<uint4*>(ptexu);
        uint4 a; a.x = t0; a.y = t1; a.z = t2; a.w = 0u;
        uint4 c; c.x = u0; c.y = u1; c.z = u2; c.w = 0u;
        p[(size_t)i * 2 + 0] = a;
        p[(size_t)i * 2 + 1] = c;
    } else {
        const size_t o = (size_t)i * 6;
        ptexu[o + 0] = t0; ptexu[o + 1] = t1; ptexu[o + 2] = t2;
        ptexu[o + 3] = u0; ptexu[o + 4] = u1; ptexu[o + 5] = u2;
    }
}

template <bool PAD32>
__global__ __launch_bounds__(256) void render_quad(
    const unsigned* __restrict__ ptexu, const float4* __restrict__ ftab,
    const float* __restrict__ bary, const int* __restrict__ pix,
    const float* __restrict__ bkg, int F,
    float* __restrict__ render, float* __restrict__ is_valid)
{
    const int tid = blockIdx.x * blockDim.x + threadIdx.x;  // 1M, 4 px each
    const float bkg0 = bkg[0], bkg1 = bkg[1], bkg2 = bkg[2];

    int pf[4];
    #pragma unroll
    for (int j = 0; j < 4; ++j)
        pf[j] = __builtin_nontemporal_load(&pix[(j << 20) | tid]);

    float ba[4][3];
    #pragma unroll
    for (int j = 0; j < 4; ++j) {
        const size_t o = (size_t)((j << 20) | tid) * 3;
        ba[j][0] = __builtin_nontemporal_load(&bary[o + 0]);
        ba[j][1] = __builtin_nontemporal_load(&bary[o + 1]);
        ba[j][2] = __builtin_nontemporal_load(&bary[o + 2]);
    }

    float4 A[4], Bv[4];
    #pragma unroll
    for (int j = 0; j < 4; ++j) {
        const int lf = (pf[j] != -1) ? pf[j] - j * F : 0;
        A[j]  = ftab[lf * 2 + 0];
        Bv[j] = ftab[lf * 2 + 1];
    }

    unsigned t0[4], t1[4], t2[4], u0[4], u1[4], u2[4];
    float wx[4], wy[4];
    #pragma unroll
    for (int j = 0; j < 4; ++j) {
        const float u = ba[j][0] * A[j].x + ba[j][1] * A[j].z + ba[j][2] * Bv[j].x;
        const float v = ba[j][0] * A[j].y + ba[j][1] * A[j].w + ba[j][2] * Bv[j].y;
        float x = fminf(fmaxf(u * 1023.0f, 0.0f), 1023.0f);
        float y = fminf(fmaxf(v * 1023.0f, 0.0f), 1023.0f);
        if (pf[j] == -1) { x = 0.0f; y = 0.0f; }
        const float xf = floorf(x), yf = floorf(y);
        wx[j] = x - xf; wy[j] = y - yf;
        const int e = (j << 20) | (((int)yf) << 10) | (int)xf;
        if (PAD32) {
            const uint4* p = reinterpret_cast<const uint4*>(ptexu);
            const uint4 qt = p[(size_t)e * 2 + 0];
            const uint4 qb = p[(size_t)e * 2 + 1];
            t0[j] = qt.x; t1[j] = qt.y; t2[j] = qt.z;
            u0[j] = qb.x; u1[j] = qb.y; u2[j] = qb.z;
        } else {
            const size_t o = (size_t)e * 6;
            t0[j] = ptexu[o + 0]; t1[j] = ptexu[o + 1]; t2[j] = ptexu[o + 2];
            u0[j] = ptexu[o + 3]; u1[j] = ptexu[o + 4]; u2[j] = ptexu[o + 5];
        }
    }

    #pragma unroll
    for (int j = 0; j < 4; ++j) {
        const float2 a01 = h2f(t0[j]), a2b = h2f(t1[j]), a12 = h2f(t2[j]);
        const float2 c01 = h2f(u0[j]), c2b = h2f(u1[j]), c12 = h2f(u2[j]);
        const float iwx = 1.0f - wx[j], iwy = 1.0f - wy[j];
        // row L = (x.x, x.y, y.x), row R = (y.y, z.x, z.y)
        const float top0 = a01.x * iwx + a2b.y * wx[j];
        const float top1 = a01.y * iwx + a12.x * wx[j];
        const float top2 = a2b.x * iwx + a12.y * wx[j];
        const float bot0 = c01.x * iwx + c2b.y * wx[j];
        const float bot1 = c01.y * iwx + c12.x * wx[j];
        const float bot2 = c2b.x * iwx + c12.y * wx[j];
        float r0 = top0 * iwy + bot0 * wy[j];
        float r1 = top1 * iwy + bot1 * wy[j];
        float r2 = top2 * iwy + bot2 * wy[j];
        float vf = 1.0f;
        if (pf[j] == -1) { r0 = bkg0; r1 = bkg1; r2 = bkg2; vf = 0.0f; }
        const int ob = (j * 3) << 20;
        __builtin_nontemporal_store(r0, &render[ob | tid]);
        __builtin_nontemporal_store(r1, &render[(ob + HWT) | tid]);
        __builtin_nontemporal_store(r2, &render[(ob + 2 * HWT) | tid]);
        __builtin_nontemporal_store(vf, &is_valid[(j << 20) | tid]);
    }
}

// ---------- no-workspace safety fallback (direct planar gather) ----------
__global__ __launch_bounds__(256) void uvrender_direct(
    const float* __restrict__ bary, const float* __restrict__ uvmap,
    const float* __restrict__ vertex_uv, const float* __restrict__ bkg,
    const int* __restrict__ pix_to_face, const int* __restrict__ face_uv,
    int F, float* __restrict__ render, float* __restrict__ is_valid)
{
    const int total = BB * HWT;
    const float bkg0 = bkg[0], bkg1 = bkg[1], bkg2 = bkg[2];
    for (int idx = blockIdx.x * blockDim.x + threadIdx.x; idx < total;
         idx += gridDim.x * blockDim.x) {
        const int b  = idx >> 20;
        const int hw = idx & (HWT - 1);
        const int pf = pix_to_face[idx];
        float r0 = bkg0, r1 = bkg1, r2 = bkg2, vflag = 0.0f;
        if (pf != -1) {
            vflag = 1.0f;
            const int local = pf - b * F;
            const int i0 = face_uv[local * 3 + 0];
            const int i1 = face_uv[local * 3 + 1];
            const int i2 = face_uv[local * 3 + 2];
            const float b0 = bary[(size_t)idx * 3 + 0];
            const float b1 = bary[(size_t)idx * 3 + 1];
            const float b2 = bary[(size_t)idx * 3 + 2];
            const float u = b0 * vertex_uv[i0 * 2] + b1 * vertex_uv[i1 * 2] +
                            b2 * vertex_uv[i2 * 2];
            const float v = b0 * (1.0f - vertex_uv[i0 * 2 + 1]) +
                            b1 * (1.0f - vertex_uv[i1 * 2 + 1]) +
                            b2 * (1.0f - vertex_uv[i2 * 2 + 1]);
            float x = fminf(fmaxf(u * 1023.0f, 0.0f), 1023.0f);
            float y = fminf(fmaxf(v * 1023.0f, 0.0f), 1023.0f);
            const float xf = floorf(x), yf = floorf(y);
            const int x0 = (int)xf, y0 = (int)yf;
            const int x1 = min(x0 + 1, WMASK), y1 = min(y0 + 1, WMASK);
            const float wx = x - xf, wy = y - yf;
            const float iwx = 1.0f - wx, iwy = 1.0f - wy;
            const float* texb = uvmap + ((size_t)b * 3 << 20);
            float out[3];
            #pragma unroll
            for (int c = 0; c < 3; ++c) {
                const float* t = texb + ((size_t)c << 20);
                const float t00 = t[(y0 << 10) | x0];
                const float t01 = t[(y0 << 10) | x1];
                const float t10 = t[(y1 << 10) | x0];
                const float t11 = t[(y1 << 10) | x1];
                out[c] = (t00 * iwx + t01 * wx) * iwy + (t10 * iwx + t11 * wx) * wy;
            }
            r0 = out[0]; r1 = out[1]; r2 = out[2];
        }
        const size_t ob = (size_t)b * 3 * HWT + hw;
        __builtin_nontemporal_store(r0, &render[ob]);
        __builtin_nontemporal_store(r1, &render[ob + HWT]);
        __builtin_nontemporal_store(r2, &render[ob + 2 * (size_t)HWT]);
        __builtin_nontemporal_store(vflag, &is_valid[idx]);
    }
}

extern "C" void kernel_launch(void* const* d_in, const int* in_sizes, int n_in,
                              void* d_out, int out_size, void* d_ws, size_t ws_size,
                              hipStream_t stream) {
    const float* bary        = (const float*)d_in[0];
    const float* uvmap       = (const float*)d_in[1];
    const float* vertex_uv   = (const float*)d_in[2];
    const float* bkg         = (const float*)d_in[3];
    const int*   pix_to_face = (const int*)d_in[4];
    const int*   face_uv     = (const int*)d_in[5];
    const int F = in_sizes[5] / 3;   // 40000

    float* render   = (float*)d_out;
    float* is_valid = (float*)d_out + (size_t)BB * 3 * HWT;

    const size_t Q32_B  = (size_t)BB * HWT * 32;            // 128 MiB
    const size_t Q24_B  = (size_t)BB * HWT * 24;            //  96 MiB
    const size_t FTAB_B = (size_t)F * 2 * sizeof(float4);   // ~1.25 MiB

    if (ws_size >= Q32_B + FTAB_B) {
        unsigned* ptexu = (unsigned*)d_ws;
        float4*   ftab  = (float4*)((char*)d_ws + Q32_B);
        build_ftab<<<(F + 255) / 256, 256, 0, stream>>>(face_uv, vertex_uv, ftab, F);
        pack_quad<true><<<(BB * HWT) / 256, 256, 0, stream>>>(uvmap, ptexu);
        render_quad<true><<<HWT / 256, 256, 0, stream>>>(
            ptexu, ftab, bary, pix_to_face, bkg, F, render, is_valid);
    } else if (ws_size >= Q24_B + FTAB_B) {
        unsigned* ptexu = (unsigned*)d_ws;
        float4*   ftab  = (float4*)((char*)d_ws + Q24_B);
        build_ftab<<<(F + 255) / 256, 256, 0, stream>>>(face_uv, vertex_uv, ftab, F);
        pack_quad<false><<<(BB * HWT) / 256, 256, 0, stream>>>(uvmap, ptexu);
        render_quad<false><<<HWT / 256, 256, 0, stream>>>(
            ptexu, ftab, bary, pix_to_face, bkg, F, render, is_valid);
    } else {
        uvrender_direct<<<2048, 256, 0, stream>>>(
            bary, uvmap, vertex_uv, bkg, pix_to_face, face_uv, F,
            render, is_valid);
    }
}